// Round 5
// baseline (406.146 us; speedup 1.0000x reference)
//
#include <hip/hip_runtime.h>

// BiCutLoss: out = (sum_{label==1} 0.7*out[...,0] + sum_{label!=1} 1.3*out[...,1]) / B
// output: [B, L, 2] fp32, labels: [B, L] int32. Pure BW-bound reduction:
// 201 MB read -> ~30 us floor at the ~6.8 TB/s this chip demonstrates.
// Single fused kernel: grid-stride streaming (nt loads, unit-stride float4/int2),
// per-block partial, last-block-done final reduction (agent-scope loads for
// cross-XCD coherence). Ticket counter zeroed via graph-capturable memset.

#define BICUT_BLOCKS 2048
#define BICUT_THREADS 256

typedef float f32x4 __attribute__((ext_vector_type(4)));
typedef int   i32x2 __attribute__((ext_vector_type(2)));

__global__ __launch_bounds__(BICUT_THREADS) void bicut_fused_kernel(
    const float* __restrict__ outp,    // [n_pairs * 2]
    const int*   __restrict__ labs,    // [n_pairs]
    float* __restrict__ partials,      // [gridDim.x] in d_ws
    unsigned int* __restrict__ ticket, // 1 uint in d_ws (pre-zeroed)
    float* __restrict__ out,
    int n_f4,                          // n_pairs / 2
    int n_pairs,
    float inv_b)
{
    const float CPOS = 0.7f;   // (1-alpha)/r
    const float CNEG = 1.3f;   // alpha/(1-r)

    const f32x4* out4 = (const f32x4*)outp;  // 1 float4 = pairs {2i, 2i+1}
    const i32x2* lab2 = (const i32x2*)labs;  // labels  {2i, 2i+1}

    float acc = 0.0f;
    int stride = gridDim.x * blockDim.x;
    int tid = blockIdx.x * blockDim.x + threadIdx.x;
    #pragma unroll 8
    for (int i = tid; i < n_f4; i += stride) {
        f32x4 a = __builtin_nontemporal_load(&out4[i]);
        i32x2 l = __builtin_nontemporal_load(&lab2[i]);
        acc += (l.x == 1) ? CPOS * a.x : CNEG * a.y;
        acc += (l.y == 1) ? CPOS * a.z : CNEG * a.w;
    }
    // scalar tail (empty for 8192*2048)
    for (int i = 2 * n_f4 + tid; i < n_pairs; i += stride) {
        acc += (labs[i] == 1) ? CPOS * outp[2 * i] : CNEG * outp[2 * i + 1];
    }

    // wave-64 reduction
    #pragma unroll
    for (int off = 32; off > 0; off >>= 1)
        acc += __shfl_down(acc, off, 64);

    __shared__ float lds[BICUT_THREADS / 64];
    __shared__ bool last;
    int lane = threadIdx.x & 63;
    int wave = threadIdx.x >> 6;
    if (lane == 0) lds[wave] = acc;
    __syncthreads();
    if (threadIdx.x == 0) {
        float s = 0.0f;
        #pragma unroll
        for (int w = 0; w < BICUT_THREADS / 64; ++w) s += lds[w];
        // agent-scope store so other XCDs' reads see it
        __hip_atomic_store(&partials[blockIdx.x], s, __ATOMIC_RELAXED,
                           __HIP_MEMORY_SCOPE_AGENT);
        __threadfence();  // device-scope release of the partial
        unsigned int v = __hip_atomic_fetch_add(ticket, 1u, __ATOMIC_ACQ_REL,
                                                __HIP_MEMORY_SCOPE_AGENT);
        last = (v == gridDim.x - 1);
    }
    __syncthreads();

    if (last) {
        __threadfence();  // acquire side
        float a2 = 0.0f;
        int nb = gridDim.x;
        for (int i = threadIdx.x; i < nb; i += BICUT_THREADS)
            a2 += __hip_atomic_load(&partials[i], __ATOMIC_RELAXED,
                                    __HIP_MEMORY_SCOPE_AGENT);
        #pragma unroll
        for (int off = 32; off > 0; off >>= 1)
            a2 += __shfl_down(a2, off, 64);
        if (lane == 0) lds[wave] = a2;
        __syncthreads();
        if (threadIdx.x == 0) {
            float s = 0.0f;
            #pragma unroll
            for (int w = 0; w < BICUT_THREADS / 64; ++w) s += lds[w];
            out[0] = s * inv_b;
        }
    }
}

extern "C" void kernel_launch(void* const* d_in, const int* in_sizes, int n_in,
                              void* d_out, int out_size, void* d_ws, size_t ws_size,
                              hipStream_t stream) {
    const float* output = (const float*)d_in[0];     // [B, L, 2] fp32
    const int*   labels = (const int*)d_in[1];       // [B, L] int32
    float* out = (float*)d_out;
    float* partials = (float*)d_ws;                  // BICUT_BLOCKS floats
    unsigned int* ticket = (unsigned int*)(partials + BICUT_BLOCKS);

    int n_pairs = in_sizes[1];                       // B*L = 16,777,216
    int n_f4 = n_pairs / 2;
    const float inv_b = 1.0f / 8192.0f;              // B fixed by reference setup

    hipMemsetAsync(ticket, 0, sizeof(unsigned int), stream);  // capturable memset node
    bicut_fused_kernel<<<BICUT_BLOCKS, BICUT_THREADS, 0, stream>>>(
        output, labels, partials, ticket, out, n_f4, n_pairs, inv_b);
}

// Round 7
// 217.098 us; speedup vs baseline: 1.8708x; 1.8708x over previous
//
#include <hip/hip_runtime.h>

// BiCutLoss: out = (sum_{label==1} 0.7*out[...,0] + sum_{label!=1} 1.3*out[...,1]) / B
// output: [B, L, 2] fp32, labels: [B, L] int32. Pure BW-bound reduction:
// 201 MB read -> ~29 us floor at the ~6.9 TB/s this chip demonstrates.
//
// Two-kernel tree reduction (NO single-ticket fusion: round-5 counters showed
// 2048 same-address agent-scope atomics serialize at ~100ns each on the
// 8-XCD fabric -> 200us tail; WRITE_SIZE=128KB = 2048 cacheline writebacks).
// Kernel boundary provides cross-XCD visibility of partials for free.
//
// Streaming: all loads full dwordx4 (2x float4 = 4 contiguous pairs + 1x int4
// labels), nontemporal (single-use), unroll 4 -> ~192 B/lane in flight.

#define BICUT_BLOCKS 2048
#define BICUT_THREADS 256

typedef float f32x4 __attribute__((ext_vector_type(4)));
typedef int   i32x4 __attribute__((ext_vector_type(4)));

__global__ __launch_bounds__(BICUT_THREADS) void bicut_partial_kernel(
    const float* __restrict__ outp,    // [n_pairs * 2]
    const int*   __restrict__ labs,    // [n_pairs]
    float* __restrict__ partials,
    int n_quads,                       // n_pairs / 4
    int n_pairs)
{
    const float CPOS = 0.7f;   // (1-alpha)/r
    const float CNEG = 1.3f;   // alpha/(1-r)

    const f32x4* out4 = (const f32x4*)outp;  // quad q: floats at 2q, 2q+1
    const i32x4* lab4 = (const i32x4*)labs;  // quad q: labels 4q..4q+3

    float acc = 0.0f;
    int stride = gridDim.x * blockDim.x;
    int tid = blockIdx.x * blockDim.x + threadIdx.x;
    #pragma unroll 4
    for (int q = tid; q < n_quads; q += stride) {
        f32x4 a = __builtin_nontemporal_load(&out4[2 * q]);      // pairs 4q,4q+1
        f32x4 b = __builtin_nontemporal_load(&out4[2 * q + 1]);  // pairs 4q+2,4q+3
        i32x4 l = __builtin_nontemporal_load(&lab4[q]);
        acc += (l.x == 1) ? CPOS * a.x : CNEG * a.y;
        acc += (l.y == 1) ? CPOS * a.z : CNEG * a.w;
        acc += (l.z == 1) ? CPOS * b.x : CNEG * b.y;
        acc += (l.w == 1) ? CPOS * b.z : CNEG * b.w;
    }
    // scalar tail (empty for 8192*2048)
    for (int i = 4 * n_quads + tid; i < n_pairs; i += stride) {
        acc += (labs[i] == 1) ? CPOS * outp[2 * i] : CNEG * outp[2 * i + 1];
    }

    // wave-64 reduction
    #pragma unroll
    for (int off = 32; off > 0; off >>= 1)
        acc += __shfl_down(acc, off, 64);

    __shared__ float lds[BICUT_THREADS / 64];
    int lane = threadIdx.x & 63;
    int wave = threadIdx.x >> 6;
    if (lane == 0) lds[wave] = acc;
    __syncthreads();
    if (threadIdx.x == 0) {
        float s = 0.0f;
        #pragma unroll
        for (int w = 0; w < BICUT_THREADS / 64; ++w) s += lds[w];
        partials[blockIdx.x] = s;
    }
}

__global__ __launch_bounds__(BICUT_THREADS) void bicut_final_kernel(
    const float* __restrict__ partials,
    float* __restrict__ out,
    int n,                 // number of partials
    float inv_b)           // 1/B
{
    float acc = 0.0f;
    for (int i = threadIdx.x; i < n; i += BICUT_THREADS) acc += partials[i];

    #pragma unroll
    for (int off = 32; off > 0; off >>= 1)
        acc += __shfl_down(acc, off, 64);

    __shared__ float lds[BICUT_THREADS / 64];
    int lane = threadIdx.x & 63;
    int wave = threadIdx.x >> 6;
    if (lane == 0) lds[wave] = acc;
    __syncthreads();
    if (threadIdx.x == 0) {
        float s = 0.0f;
        #pragma unroll
        for (int w = 0; w < BICUT_THREADS / 64; ++w) s += lds[w];
        out[0] = s * inv_b;
    }
}

extern "C" void kernel_launch(void* const* d_in, const int* in_sizes, int n_in,
                              void* d_out, int out_size, void* d_ws, size_t ws_size,
                              hipStream_t stream) {
    const float* output = (const float*)d_in[0];     // [B, L, 2] fp32
    const int*   labels = (const int*)d_in[1];       // [B, L] int32
    float* out = (float*)d_out;
    float* partials = (float*)d_ws;                  // BICUT_BLOCKS floats

    int n_pairs = in_sizes[1];                       // B*L = 16,777,216
    int n_quads = n_pairs / 4;
    const float inv_b = 1.0f / 8192.0f;              // B fixed by reference setup

    bicut_partial_kernel<<<BICUT_BLOCKS, BICUT_THREADS, 0, stream>>>(
        output, labels, partials, n_quads, n_pairs);
    bicut_final_kernel<<<1, BICUT_THREADS, 0, stream>>>(
        partials, out, BICUT_BLOCKS, inv_b);
}